// Round 1
// baseline (17764.044 us; speedup 1.0000x reference)
//
#include <hip/hip_runtime.h>
#include <hip/hip_bf16.h>
#include <math.h>

#define B_   128
#define P_   196
#define ENC_ 2048
#define A_   512
#define H_   512
#define E_   512
#define V_   10000
#define T_   20

__device__ __forceinline__ float sigmoidf_(float x) { return 1.0f / (1.0f + expf(-x)); }

// C[M,N] = A[M,K] @ B[N,K]^T + bias[N]  (+ C if accumulate) (* rowmask(lengths,t) if lengths)
// 64x64 block tile, 16 K-tile, 256 threads, 4x4 micro-tile per thread. Pure fp32.
__global__ __launch_bounds__(256) void gemm_nt(
    const float* __restrict__ A, const float* __restrict__ Bm,
    float* __restrict__ C, const float* __restrict__ bias,
    int M, int N, int K, int lda, int ldb, int ldc,
    int accumulate, const int* __restrict__ lengths, int t)
{
    __shared__ float As[16][65];
    __shared__ float Bs[16][65];
    const int bm = blockIdx.y * 64;
    const int bn = blockIdx.x * 64;
    const int tid = threadIdx.x;
    const int tx = tid & 15, ty = tid >> 4;
    float acc[4][4] = {};
    for (int k0 = 0; k0 < K; k0 += 16) {
        #pragma unroll
        for (int i = 0; i < 4; i++) {
            int idx = tid + i * 256;       // 0..1023
            int r = idx >> 4;              // 0..63
            int k = idx & 15;
            int gm = bm + r;
            int gn = bn + r;
            As[k][r] = (gm < M) ? A[(size_t)gm * lda + k0 + k] : 0.0f;
            Bs[k][r] = (gn < N) ? Bm[(size_t)gn * ldb + k0 + k] : 0.0f;
        }
        __syncthreads();
        #pragma unroll
        for (int k = 0; k < 16; k++) {
            float a[4], bb[4];
            #pragma unroll
            for (int i = 0; i < 4; i++) a[i] = As[k][ty * 4 + i];
            #pragma unroll
            for (int j = 0; j < 4; j++) bb[j] = Bs[k][tx * 4 + j];
            #pragma unroll
            for (int i = 0; i < 4; i++)
                #pragma unroll
                for (int j = 0; j < 4; j++) acc[i][j] += a[i] * bb[j];
        }
        __syncthreads();
    }
    #pragma unroll
    for (int i = 0; i < 4; i++) {
        int gm = bm + ty * 4 + i;
        if (gm >= M) continue;
        float rs = 1.0f;
        if (lengths) rs = (t < lengths[gm] - 1) ? 1.0f : 0.0f;
        #pragma unroll
        for (int j = 0; j < 4; j++) {
            int gn = bn + tx * 4 + j;
            if (gn >= N) continue;
            float v = acc[i][j];
            if (bias) v += bias[gn];
            if (accumulate) v += C[(size_t)gm * ldc + gn];
            C[(size_t)gm * ldc + gn] = v * rs;
        }
    }
}

// mean over P axis: meanE[b,e] = (1/P) sum_p enc[b,p,e]
__global__ __launch_bounds__(256) void mean_kernel(const float* __restrict__ enc,
                                                   float* __restrict__ meanE)
{
    int idx = blockIdx.x * 256 + threadIdx.x;     // B*ENC
    int b = idx >> 11, e = idx & 2047;
    const float* p = enc + (size_t)b * P_ * ENC_ + e;
    float s = 0.0f;
    for (int i = 0; i < P_; i++) s += p[(size_t)i * ENC_];
    meanE[idx] = s * (1.0f / (float)P_);
}

// x_in[b, 0:E] = emb_table[captions[b, t]]
__global__ __launch_bounds__(256) void emb_kernel(const int* __restrict__ captions,
                                                  const float* __restrict__ table,
                                                  float* __restrict__ x_in, int t)
{
    int idx = blockIdx.x * 256 + threadIdx.x;     // B*E
    int b = idx >> 9, col = idx & 511;
    int tok = captions[b * (T_ + 1) + t];
    x_in[(size_t)b * (E_ + ENC_) + col] = table[(size_t)tok * E_ + col];
}

// e[b,p] = sum_a relu(att1[b,p,a] + att2[b,a]) * w[a] + b_full
// one 64-lane wave per (b,p) row; 4 rows per block
__global__ __launch_bounds__(256) void e_kernel(const float* __restrict__ att1,
                                                const float* __restrict__ att2,
                                                const float* __restrict__ w,
                                                const float* __restrict__ bfull,
                                                float* __restrict__ e)
{
    int row = blockIdx.x * 4 + (threadIdx.x >> 6);  // b*P + p
    int lane = threadIdx.x & 63;
    if (row >= B_ * P_) return;
    int b = row / P_;
    const float* a1 = att1 + (size_t)row * A_;
    const float* a2 = att2 + (size_t)b * A_;
    float s = 0.0f;
    #pragma unroll
    for (int a = 0; a < A_ / 64; a++) {
        int ai = lane + a * 64;
        float v = a1[ai] + a2[ai];
        s += (v > 0.0f ? v : 0.0f) * w[ai];
    }
    #pragma unroll
    for (int off = 32; off > 0; off >>= 1) s += __shfl_down(s, off, 64);
    if (lane == 0) e[row] = s + bfull[0];
}

// alpha[b,:] = softmax(e[b,:]) over P
__global__ __launch_bounds__(256) void softmax_kernel(const float* __restrict__ e,
                                                      float* __restrict__ alpha)
{
    __shared__ float red[256];
    __shared__ float smax, ssum;
    int b = blockIdx.x;
    int tid = threadIdx.x;
    const float* eb = e + (size_t)b * P_;
    float v = (tid < P_) ? eb[tid] : -1e30f;
    red[tid] = v;
    __syncthreads();
    for (int s = 128; s > 0; s >>= 1) {
        if (tid < s) red[tid] = fmaxf(red[tid], red[tid + s]);
        __syncthreads();
    }
    if (tid == 0) smax = red[0];
    __syncthreads();
    float ex = (tid < P_) ? expf(v - smax) : 0.0f;
    red[tid] = ex;
    __syncthreads();
    for (int s = 128; s > 0; s >>= 1) {
        if (tid < s) red[tid] += red[tid + s];
        __syncthreads();
    }
    if (tid == 0) ssum = red[0];
    __syncthreads();
    if (tid < P_) alpha[(size_t)b * P_ + tid] = ex / ssum;
}

// x_in[b, E + e'] = sigmoid(fbeta_pre[b,e']) * sum_p alpha[b,p] * enc[b,p,e']
__global__ __launch_bounds__(256) void ctx_kernel(const float* __restrict__ alpha,
                                                  const float* __restrict__ enc,
                                                  const float* __restrict__ fbeta_pre,
                                                  float* __restrict__ x_in)
{
    __shared__ float al[P_];
    int b = blockIdx.y;
    int ecol = blockIdx.x * 256 + threadIdx.x;    // 0..ENC-1
    if (threadIdx.x < P_) al[threadIdx.x] = alpha[(size_t)b * P_ + threadIdx.x];
    __syncthreads();
    const float* encb = enc + (size_t)b * P_ * ENC_;
    float s = 0.0f;
    for (int p = 0; p < P_; p++) s += al[p] * encb[(size_t)p * ENC_ + ecol];
    float gate = sigmoidf_(fbeta_pre[(size_t)b * ENC_ + ecol]);
    x_in[(size_t)b * (E_ + ENC_) + E_ + ecol] = gate * s;
}

// LSTM pointwise: gates -> c_new, h_new; masked update of h, c
__global__ __launch_bounds__(256) void lstm_kernel(const float* __restrict__ gates,
                                                   float* __restrict__ h,
                                                   float* __restrict__ c,
                                                   float* __restrict__ h_new,
                                                   const int* __restrict__ lengths, int t)
{
    int idx = blockIdx.x * 256 + threadIdx.x;     // B*H
    int b = idx >> 9, j = idx & 511;
    const float* g = gates + (size_t)b * 4 * H_;
    float i_ = sigmoidf_(g[j]);
    float f_ = sigmoidf_(g[H_ + j]);
    float g_ = tanhf(g[2 * H_ + j]);
    float o_ = sigmoidf_(g[3 * H_ + j]);
    float cn = f_ * c[idx] + i_ * g_;
    float hn = o_ * tanhf(cn);
    h_new[idx] = hn;
    bool m = t < lengths[b] - 1;
    h[idx] = m ? hn : h[idx];
    c[idx] = m ? cn : c[idx];
}

extern "C" void kernel_launch(void* const* d_in, const int* in_sizes, int n_in,
                              void* d_out, int out_size, void* d_ws, size_t ws_size,
                              hipStream_t stream)
{
    const float* enc      = (const float*)d_in[0];
    const int*   captions = (const int*)  d_in[1];
    const int*   lengths  = (const int*)  d_in[2];
    const float* W_enc    = (const float*)d_in[3];
    const float* b_enc    = (const float*)d_in[4];
    const float* W_dec    = (const float*)d_in[5];
    const float* b_dec    = (const float*)d_in[6];
    const float* w_full   = (const float*)d_in[7];
    const float* b_full   = (const float*)d_in[8];
    const float* emb_tab  = (const float*)d_in[9];
    const float* W_ih     = (const float*)d_in[10];
    const float* b_ih     = (const float*)d_in[11];
    const float* W_hh     = (const float*)d_in[12];
    const float* b_hh     = (const float*)d_in[13];
    const float* W_init_h = (const float*)d_in[14];
    const float* b_init_h = (const float*)d_in[15];
    const float* W_init_c = (const float*)d_in[16];
    const float* b_init_c = (const float*)d_in[17];
    const float* W_fbeta  = (const float*)d_in[18];
    const float* b_fbeta  = (const float*)d_in[19];
    const float* W_fc     = (const float*)d_in[20];
    const float* b_fc     = (const float*)d_in[21];
    float* out = (float*)d_out;

    float* ws = (float*)d_ws;
    size_t off = 0;
    auto alloc = [&](size_t n) { float* p = ws + off; off += n; return p; };
    float* att1  = alloc((size_t)B_ * P_ * A_);    // 12.8M
    float* meanE = alloc((size_t)B_ * ENC_);
    float* h     = alloc((size_t)B_ * H_);
    float* c     = alloc((size_t)B_ * H_);
    float* hn    = alloc((size_t)B_ * H_);
    float* att2  = alloc((size_t)B_ * A_);
    float* fbeta = alloc((size_t)B_ * ENC_);
    float* e     = alloc((size_t)B_ * P_);
    float* alpha = alloc((size_t)B_ * P_);
    float* x_in  = alloc((size_t)B_ * (E_ + ENC_));
    float* gates = alloc((size_t)B_ * 4 * H_);

    // att1 = enc @ W_enc^T + b_enc   [25088 x 512, K=2048]
    gemm_nt<<<dim3(A_ / 64, (B_ * P_) / 64), 256, 0, stream>>>(
        enc, W_enc, att1, b_enc, B_ * P_, A_, ENC_, ENC_, ENC_, A_, 0, nullptr, 0);
    // mean_enc
    mean_kernel<<<(B_ * ENC_) / 256, 256, 0, stream>>>(enc, meanE);
    // h0 / c0
    gemm_nt<<<dim3(H_ / 64, B_ / 64), 256, 0, stream>>>(
        meanE, W_init_h, h, b_init_h, B_, H_, ENC_, ENC_, ENC_, H_, 0, nullptr, 0);
    gemm_nt<<<dim3(H_ / 64, B_ / 64), 256, 0, stream>>>(
        meanE, W_init_c, c, b_init_c, B_, H_, ENC_, ENC_, ENC_, H_, 0, nullptr, 0);

    for (int t = 0; t < T_; t++) {
        emb_kernel<<<(B_ * E_) / 256, 256, 0, stream>>>(captions, emb_tab, x_in, t);
        // att2 = h @ W_dec^T + b_dec    [128 x 512, K=512]
        gemm_nt<<<dim3(A_ / 64, B_ / 64), 256, 0, stream>>>(
            h, W_dec, att2, b_dec, B_, A_, H_, H_, H_, A_, 0, nullptr, 0);
        // fbeta_pre = h @ W_fbeta^T + b_fbeta   [128 x 2048, K=512]
        gemm_nt<<<dim3(ENC_ / 64, B_ / 64), 256, 0, stream>>>(
            h, W_fbeta, fbeta, b_fbeta, B_, ENC_, H_, H_, H_, ENC_, 0, nullptr, 0);
        // e = relu(att1 + att2) . w + b_full
        e_kernel<<<(B_ * P_) / 4, 256, 0, stream>>>(att1, att2, w_full, b_full, e);
        softmax_kernel<<<B_, 256, 0, stream>>>(e, alpha);
        // x_in[:, E:] = sigmoid(fbeta_pre) * (alpha @ enc)
        ctx_kernel<<<dim3(ENC_ / 256, B_), 256, 0, stream>>>(alpha, enc, fbeta, x_in);
        // gates = x_in @ W_ih^T + b_ih        [128 x 2048, K=2560]
        gemm_nt<<<dim3((4 * H_) / 64, B_ / 64), 256, 0, stream>>>(
            x_in, W_ih, gates, b_ih, B_, 4 * H_, E_ + ENC_, E_ + ENC_, E_ + ENC_, 4 * H_, 0, nullptr, 0);
        // gates += h @ W_hh^T + b_hh          [128 x 2048, K=512]
        gemm_nt<<<dim3((4 * H_) / 64, B_ / 64), 256, 0, stream>>>(
            h, W_hh, gates, b_hh, B_, 4 * H_, H_, H_, H_, 4 * H_, 1, nullptr, 0);
        lstm_kernel<<<(B_ * H_) / 256, 256, 0, stream>>>(gates, h, c, hn, lengths, t);
        // pred_t = (h_new @ W_fc^T + b_fc) * mask ; write to out[b, t, :]
        gemm_nt<<<dim3((V_ + 63) / 64, B_ / 64), 256, 0, stream>>>(
            hn, W_fc, out + (size_t)t * V_, b_fc, B_, V_, H_, H_, H_, T_ * V_, 0, lengths, t);
    }
}

// Round 2
// 4785.959 us; speedup vs baseline: 3.7117x; 3.7117x over previous
//
#include <hip/hip_runtime.h>
#include <hip/hip_bf16.h>
#include <math.h>

#define B_   128
#define P_   196
#define ENC_ 2048
#define A_   512
#define H_   512
#define E_   512
#define V_   10000
#define T_   20
#define XK_  3072   /* x_in width: E + ENC + H */

typedef __attribute__((ext_vector_type(8))) short bf16x8;
typedef __attribute__((ext_vector_type(4))) float f32x4;

__device__ __forceinline__ float sigmoidf_(float x) { return 1.0f / (1.0f + expf(-x)); }

__device__ __forceinline__ short f2bf(float f) {
    unsigned u = __float_as_uint(f);
    u += 0x7fffu + ((u >> 16) & 1u);
    return (short)(u >> 16);
}

__device__ __forceinline__ void gload_lds16(const void* g, void* l) {
    __builtin_amdgcn_global_load_lds(
        (const __attribute__((address_space(1))) void*)g,
        (__attribute__((address_space(3))) void*)l, 16, 0, 0);
}

#define BM 128
#define BN 64
#define BK 64

// C[M,N] = A_f32[M,K] @ B_bf16[N,K]^T + bias[N]  (optional row mask via lengths/t)
__global__ __launch_bounds__(256) void gemm_bf16(
    const float* __restrict__ A, const short* __restrict__ Bm,
    float* __restrict__ C, const float* __restrict__ bias,
    int M, int N, int K, int lda, int ldb, int ldc,
    const int* __restrict__ lengths, int t)
{
    __shared__ __attribute__((aligned(16))) short As[BM * BK];
    __shared__ __attribute__((aligned(16))) short Bs[BN * BK];
    const int bm = blockIdx.y * BM;
    const int bn = blockIdx.x * BN;
    const int tid  = threadIdx.x;
    const int w    = tid >> 6;
    const int lane = tid & 63;
    const int wr = w >> 1, wc = w & 1;
    const int lrow8 = lane >> 3;   // 0..7
    const int lk    = lane & 7;    // 16B-block within 64-elem row

    f32x4 zero4 = {0.f, 0.f, 0.f, 0.f};
    f32x4 acc[4][2];
    #pragma unroll
    for (int i = 0; i < 4; i++)
        #pragma unroll
        for (int j = 0; j < 2; j++) acc[i][j] = zero4;

    for (int k0 = 0; k0 < K; k0 += BK) {
        #pragma unroll
        for (int i = 0; i < 4; i++) {
            int row = w * 32 + i * 8 + lrow8;
            const float* ga = A + (size_t)(bm + row) * lda + k0 + ((lk ^ lrow8) << 3);
            float4 f0 = *(const float4*)ga;
            float4 f1 = *(const float4*)(ga + 4);
            bf16x8 v;
            v[0] = f2bf(f0.x); v[1] = f2bf(f0.y); v[2] = f2bf(f0.z); v[3] = f2bf(f0.w);
            v[4] = f2bf(f1.x); v[5] = f2bf(f1.y); v[6] = f2bf(f1.z); v[7] = f2bf(f1.w);
            *(bf16x8*)&As[row * BK + (lk << 3)] = v;
        }
        #pragma unroll
        for (int i = 0; i < 2; i++) {
            int row = w * 16 + i * 8 + lrow8;
            int gn = bn + row; if (gn > N - 1) gn = N - 1;
            const short* gb = Bm + (size_t)gn * ldb + k0 + ((lk ^ lrow8) << 3);
            gload_lds16(gb, &Bs[(w * 16 + i * 8) * BK]);
        }
        __syncthreads();
        #pragma unroll
        for (int kk = 0; kk < BK; kk += 32) {
            const int kb = (kk >> 3) + (lane >> 4);
            bf16x8 a[4], b[2];
            #pragma unroll
            for (int i = 0; i < 4; i++) {
                int r = wr * 64 + i * 16 + (lane & 15);
                a[i] = *(const bf16x8*)&As[r * BK + ((kb ^ (r & 7)) << 3)];
            }
            #pragma unroll
            for (int j = 0; j < 2; j++) {
                int cc = wc * 32 + j * 16 + (lane & 15);
                b[j] = *(const bf16x8*)&Bs[cc * BK + ((kb ^ (cc & 7)) << 3)];
            }
            #pragma unroll
            for (int i = 0; i < 4; i++)
                #pragma unroll
                for (int j = 0; j < 2; j++)
                    acc[i][j] = __builtin_amdgcn_mfma_f32_16x16x32_bf16(a[i], b[j], acc[i][j], 0, 0, 0);
        }
        __syncthreads();
    }
    const int lr = lane >> 4, lc = lane & 15;
    #pragma unroll
    for (int i = 0; i < 4; i++) {
        #pragma unroll
        for (int r = 0; r < 4; r++) {
            int row = bm + wr * 64 + i * 16 + lr * 4 + r;
            float rs = 1.0f;
            if (lengths) rs = (t < lengths[row] - 1) ? 1.0f : 0.0f;
            #pragma unroll
            for (int j = 0; j < 2; j++) {
                int col = bn + wc * 32 + j * 16 + lc;
                if (col < N) C[(size_t)row * ldc + col] = (acc[i][j][r] + bias[col]) * rs;
            }
        }
    }
}

__global__ __launch_bounds__(256) void castk(const float* __restrict__ in,
                                             short* __restrict__ out, int n)
{
    int i4 = (blockIdx.x * 256 + threadIdx.x) * 4;
    if (i4 >= n) return;
    float4 f = *(const float4*)(in + i4);
    out[i4 + 0] = f2bf(f.x); out[i4 + 1] = f2bf(f.y);
    out[i4 + 2] = f2bf(f.z); out[i4 + 3] = f2bf(f.w);
}

__global__ __launch_bounds__(256) void wcat_kernel(const float* __restrict__ W_ih,
                                                   const float* __restrict__ W_hh,
                                                   short* __restrict__ out)
{
    int k = blockIdx.x * 256 + threadIdx.x;
    int n = blockIdx.y;
    float v = (k < E_ + ENC_) ? W_ih[(size_t)n * (E_ + ENC_) + k]
                              : W_hh[(size_t)n * H_ + (k - (E_ + ENC_))];
    out[(size_t)n * XK_ + k] = f2bf(v);
}

__global__ __launch_bounds__(256) void bcat_kernel(const float* __restrict__ b_ih,
                                                   const float* __restrict__ b_hh,
                                                   float* __restrict__ out)
{
    int j = blockIdx.x * 256 + threadIdx.x;
    if (j < 4 * H_) out[j] = b_ih[j] + b_hh[j];
}

__global__ __launch_bounds__(256) void mean_kernel(const float* __restrict__ enc,
                                                   float* __restrict__ meanE)
{
    int idx = blockIdx.x * 256 + threadIdx.x;
    int b = idx >> 11, e = idx & 2047;
    const float* p = enc + (size_t)b * P_ * ENC_ + e;
    float s = 0.0f;
    for (int i = 0; i < P_; i++) s += p[(size_t)i * ENC_];
    meanE[idx] = s * (1.0f / (float)P_);
}

__global__ __launch_bounds__(256) void emb_kernel(const int* __restrict__ captions,
                                                  const float* __restrict__ table,
                                                  float* __restrict__ x_in, int t)
{
    int idx = blockIdx.x * 256 + threadIdx.x;
    int b = idx >> 9, col = idx & 511;
    int tok = captions[b * (T_ + 1) + t];
    x_in[(size_t)b * XK_ + col] = table[(size_t)tok * E_ + col];
}

__global__ __launch_bounds__(256) void e_kernel(const float* __restrict__ att1,
                                                const float* __restrict__ att2,
                                                const float* __restrict__ w,
                                                const float* __restrict__ bfull,
                                                float* __restrict__ e)
{
    int row = blockIdx.x * 4 + (threadIdx.x >> 6);
    int lane = threadIdx.x & 63;
    if (row >= B_ * P_) return;
    int b = row / P_;
    const float* a1 = att1 + (size_t)row * A_;
    const float* a2 = att2 + (size_t)b * A_;
    float s = 0.0f;
    #pragma unroll
    for (int a = 0; a < A_ / 64; a++) {
        int ai = lane + a * 64;
        float v = a1[ai] + a2[ai];
        s += (v > 0.0f ? v : 0.0f) * w[ai];
    }
    #pragma unroll
    for (int off = 32; off > 0; off >>= 1) s += __shfl_down(s, off, 64);
    if (lane == 0) e[row] = s + bfull[0];
}

__global__ __launch_bounds__(256) void softmax_kernel(const float* __restrict__ e,
                                                      float* __restrict__ alpha)
{
    __shared__ float red[256];
    __shared__ float smax, ssum;
    int b = blockIdx.x;
    int tid = threadIdx.x;
    const float* eb = e + (size_t)b * P_;
    float v = (tid < P_) ? eb[tid] : -1e30f;
    red[tid] = v;
    __syncthreads();
    for (int s = 128; s > 0; s >>= 1) {
        if (tid < s) red[tid] = fmaxf(red[tid], red[tid + s]);
        __syncthreads();
    }
    if (tid == 0) smax = red[0];
    __syncthreads();
    float ex = (tid < P_) ? expf(v - smax) : 0.0f;
    red[tid] = ex;
    __syncthreads();
    for (int s = 128; s > 0; s >>= 1) {
        if (tid < s) red[tid] += red[tid + s];
        __syncthreads();
    }
    if (tid == 0) ssum = red[0];
    __syncthreads();
    if (tid < P_) alpha[(size_t)b * P_ + tid] = ex / ssum;
}

__global__ __launch_bounds__(256) void ctx_kernel(const float* __restrict__ alpha,
                                                  const float* __restrict__ enc,
                                                  const float* __restrict__ fbeta_pre,
                                                  float* __restrict__ x_in)
{
    __shared__ float al[P_];
    int b = blockIdx.y;
    int ecol = blockIdx.x * 256 + threadIdx.x;
    if (threadIdx.x < P_) al[threadIdx.x] = alpha[(size_t)b * P_ + threadIdx.x];
    __syncthreads();
    const float* encb = enc + (size_t)b * P_ * ENC_;
    float s = 0.0f;
    for (int p = 0; p < P_; p++) s += al[p] * encb[(size_t)p * ENC_ + ecol];
    float gate = sigmoidf_(fbeta_pre[(size_t)b * ENC_ + ecol]);
    x_in[(size_t)b * XK_ + E_ + ecol] = gate * s;
}

__global__ __launch_bounds__(256) void lstm_kernel(const float* __restrict__ gates,
                                                   float* __restrict__ x_in,
                                                   float* __restrict__ c,
                                                   float* __restrict__ hn_out,
                                                   const int* __restrict__ lengths, int t)
{
    int idx = blockIdx.x * 256 + threadIdx.x;
    int b = idx >> 9, j = idx & 511;
    const float* g = gates + (size_t)b * 4 * H_;
    float* hp = x_in + (size_t)b * XK_ + (E_ + ENC_) + j;
    float i_ = sigmoidf_(g[j]);
    float f_ = sigmoidf_(g[H_ + j]);
    float g_ = tanhf(g[2 * H_ + j]);
    float o_ = sigmoidf_(g[3 * H_ + j]);
    float cn = f_ * c[idx] + i_ * g_;
    float hv = o_ * tanhf(cn);
    hn_out[idx] = hv;
    bool m = t < lengths[b] - 1;
    *hp = m ? hv : *hp;
    c[idx] = m ? cn : c[idx];
}

extern "C" void kernel_launch(void* const* d_in, const int* in_sizes, int n_in,
                              void* d_out, int out_size, void* d_ws, size_t ws_size,
                              hipStream_t stream)
{
    const float* enc      = (const float*)d_in[0];
    const int*   captions = (const int*)  d_in[1];
    const int*   lengths  = (const int*)  d_in[2];
    const float* W_enc    = (const float*)d_in[3];
    const float* b_enc    = (const float*)d_in[4];
    const float* W_dec    = (const float*)d_in[5];
    const float* b_dec    = (const float*)d_in[6];
    const float* w_full   = (const float*)d_in[7];
    const float* b_full   = (const float*)d_in[8];
    const float* emb_tab  = (const float*)d_in[9];
    const float* W_ih     = (const float*)d_in[10];
    const float* b_ih     = (const float*)d_in[11];
    const float* W_hh     = (const float*)d_in[12];
    const float* b_hh     = (const float*)d_in[13];
    const float* W_init_h = (const float*)d_in[14];
    const float* b_init_h = (const float*)d_in[15];
    const float* W_init_c = (const float*)d_in[16];
    const float* b_init_c = (const float*)d_in[17];
    const float* W_fbeta  = (const float*)d_in[18];
    const float* b_fbeta  = (const float*)d_in[19];
    const float* W_fc     = (const float*)d_in[20];
    const float* b_fc     = (const float*)d_in[21];
    float* out = (float*)d_out;

    float* ws = (float*)d_ws;
    size_t off = 0;
    auto alloc = [&](size_t n) { float* p = ws + off; off += (n + 3) & ~(size_t)3; return p; };
    float* att1     = alloc((size_t)B_ * P_ * A_);
    short* Wenc_bf  = (short*)alloc((size_t)A_ * ENC_ / 2);
    short* Wdec_bf  = (short*)alloc((size_t)A_ * H_ / 2);
    short* Wfb_bf   = (short*)alloc((size_t)ENC_ * H_ / 2);
    short* Wfc_bf   = (short*)alloc((size_t)V_ * H_ / 2);
    short* Wcat_bf  = (short*)alloc((size_t)4 * H_ * XK_ / 2);
    short* Wih_bf   = (short*)alloc((size_t)H_ * ENC_ / 2);
    short* Wic_bf   = (short*)alloc((size_t)H_ * ENC_ / 2);
    float* bcat     = alloc(4 * H_);
    float* meanE    = alloc((size_t)B_ * ENC_);
    float* c        = alloc((size_t)B_ * H_);
    float* hn       = alloc((size_t)B_ * H_);
    float* att2     = alloc((size_t)B_ * A_);
    float* fbeta    = alloc((size_t)B_ * ENC_);
    float* e        = alloc((size_t)B_ * P_);
    float* alpha    = alloc((size_t)B_ * P_);
    float* x_in     = alloc((size_t)B_ * XK_);
    float* gates    = alloc((size_t)B_ * 4 * H_);

    castk<<<(A_ * ENC_ / 4 + 255) / 256, 256, 0, stream>>>(W_enc, Wenc_bf, A_ * ENC_);
    castk<<<(A_ * H_ / 4 + 255) / 256, 256, 0, stream>>>(W_dec, Wdec_bf, A_ * H_);
    castk<<<(ENC_ * H_ / 4 + 255) / 256, 256, 0, stream>>>(W_fbeta, Wfb_bf, ENC_ * H_);
    castk<<<(V_ * H_ / 4 + 255) / 256, 256, 0, stream>>>(W_fc, Wfc_bf, V_ * H_);
    castk<<<(H_ * ENC_ / 4 + 255) / 256, 256, 0, stream>>>(W_init_h, Wih_bf, H_ * ENC_);
    castk<<<(H_ * ENC_ / 4 + 255) / 256, 256, 0, stream>>>(W_init_c, Wic_bf, H_ * ENC_);
    wcat_kernel<<<dim3(XK_ / 256, 4 * H_), 256, 0, stream>>>(W_ih, W_hh, Wcat_bf);
    bcat_kernel<<<(4 * H_ + 255) / 256, 256, 0, stream>>>(b_ih, b_hh, bcat);

    gemm_bf16<<<dim3(A_ / BN, (B_ * P_) / BM), 256, 0, stream>>>(
        enc, Wenc_bf, att1, b_enc, B_ * P_, A_, ENC_, ENC_, ENC_, A_, nullptr, 0);
    mean_kernel<<<(B_ * ENC_) / 256, 256, 0, stream>>>(enc, meanE);
    gemm_bf16<<<dim3(H_ / BN, 1), 256, 0, stream>>>(
        meanE, Wih_bf, x_in + (E_ + ENC_), b_init_h, B_, H_, ENC_, ENC_, ENC_, XK_, nullptr, 0);
    gemm_bf16<<<dim3(H_ / BN, 1), 256, 0, stream>>>(
        meanE, Wic_bf, c, b_init_c, B_, H_, ENC_, ENC_, ENC_, H_, nullptr, 0);

    for (int t = 0; t < T_; t++) {
        emb_kernel<<<(B_ * E_) / 256, 256, 0, stream>>>(captions, emb_tab, x_in, t);
        gemm_bf16<<<dim3(A_ / BN, 1), 256, 0, stream>>>(
            x_in + (E_ + ENC_), Wdec_bf, att2, b_dec, B_, A_, H_, XK_, H_, A_, nullptr, 0);
        gemm_bf16<<<dim3(ENC_ / BN, 1), 256, 0, stream>>>(
            x_in + (E_ + ENC_), Wfb_bf, fbeta, b_fbeta, B_, ENC_, H_, XK_, H_, ENC_, nullptr, 0);
        e_kernel<<<(B_ * P_) / 4, 256, 0, stream>>>(att1, att2, w_full, b_full, e);
        softmax_kernel<<<B_, 256, 0, stream>>>(e, alpha);
        ctx_kernel<<<dim3(ENC_ / 256, B_), 256, 0, stream>>>(alpha, enc, fbeta, x_in);
        gemm_bf16<<<dim3((4 * H_) / BN, 1), 256, 0, stream>>>(
            x_in, Wcat_bf, gates, bcat, B_, 4 * H_, XK_, XK_, XK_, 4 * H_, nullptr, 0);
        lstm_kernel<<<(B_ * H_) / 256, 256, 0, stream>>>(gates, x_in, c, hn, lengths, t);
        gemm_bf16<<<dim3((V_ + BN - 1) / BN, 1), 256, 0, stream>>>(
            hn, Wfc_bf, out + (size_t)t * V_, b_fc, B_, V_, H_, H_, H_, T_ * V_, lengths, t);
    }
}

// Round 3
// 2793.495 us; speedup vs baseline: 6.3591x; 1.7133x over previous
//
#include <hip/hip_runtime.h>
#include <hip/hip_bf16.h>
#include <math.h>

#define B_   128
#define P_   196
#define ENC_ 2048
#define A_   512
#define H_   512
#define E_   512
#define V_   10000
#define T_   20
#define XK_  3072   /* x_in width: E + ENC + H */
#define NDF_ 2560   /* fused att2(512) + fbeta(2048) */

typedef __attribute__((ext_vector_type(8))) short bf16x8;
typedef __attribute__((ext_vector_type(4))) short bf16x4;
typedef __attribute__((ext_vector_type(4))) float f32x4;

__device__ __forceinline__ float sigmoidf_(float x) { return 1.0f / (1.0f + expf(-x)); }

__device__ __forceinline__ short f2bf(float f) {
    unsigned u = __float_as_uint(f);
    u += 0x7fffu + ((u >> 16) & 1u);
    return (short)(u >> 16);
}
__device__ __forceinline__ float bf2f(short s) {
    return __uint_as_float(((unsigned)(unsigned short)s) << 16);
}
__device__ __forceinline__ void gload_lds16(const void* g, void* l) {
    __builtin_amdgcn_global_load_lds(
        (const __attribute__((address_space(1))) void*)g,
        (__attribute__((address_space(3))) void*)l, 16, 0, 0);
}

#define BM 128
#define BN 64
#define BK 64

// C[M,N] = A_bf16[M,K] @ B_bf16[N,K]^T + bias[N]
// Double-buffered LDS; XOR-swizzled slots (pre-swizzled global source).
// mtiles>1: XCD-grouped decode so one A-panel's N-blocks share an XCD L2.
// Output fp32 (Cf) or bf16 (Cb). Optional row mask via lengths/t (pred).
__global__ __launch_bounds__(256) void gemm_bf(
    const short* __restrict__ A, const short* __restrict__ Bw,
    float* __restrict__ Cf, short* __restrict__ Cb,
    const float* __restrict__ bias,
    int N, int K, int lda, int ldb, int ldc,
    int mtiles, int ntiles,
    const int* __restrict__ lengths, int t)
{
    __shared__ __attribute__((aligned(16))) short As[2][BM * BK];
    __shared__ __attribute__((aligned(16))) short Bs[2][BN * BK];
    int pm, pn;
    if (mtiles == 1) { pm = 0; pn = blockIdx.x; }
    else {
        int xcd = blockIdx.x & 7, s = blockIdx.x >> 3;
        pn = s % ntiles;
        pm = (s / ntiles) * 8 + xcd;
        if (pm >= mtiles) return;
    }
    const int bm = pm * BM, bn = pn * BN;
    const int tid = threadIdx.x, w = tid >> 6, lane = tid & 63;
    const int wr = w >> 1, wc = w & 1;
    const int lr8 = lane >> 3, lk = lane & 7;

    f32x4 zero4 = {0.f, 0.f, 0.f, 0.f};
    f32x4 acc[4][2];
    #pragma unroll
    for (int i = 0; i < 4; i++)
        #pragma unroll
        for (int j = 0; j < 2; j++) acc[i][j] = zero4;

#define STAGE(buf, k0) {                                                        \
    _Pragma("unroll")                                                           \
    for (int i = 0; i < 4; i++) {                                               \
        int row0 = w * 32 + i * 8; int row = row0 + lr8;                        \
        const short* ga = A + (size_t)(bm + row) * lda + (k0)                   \
                          + ((lk ^ (row & 7)) << 3);                            \
        gload_lds16(ga, &As[buf][row0 * BK]);                                   \
    }                                                                           \
    _Pragma("unroll")                                                           \
    for (int i = 0; i < 2; i++) {                                               \
        int row0 = w * 16 + i * 8; int row = row0 + lr8;                        \
        int gn = bn + row; if (gn > N - 1) gn = N - 1;                          \
        const short* gb = Bw + (size_t)gn * ldb + (k0)                          \
                          + ((lk ^ (row & 7)) << 3);                            \
        gload_lds16(gb, &Bs[buf][row0 * BK]);                                   \
    } }

    STAGE(0, 0);
    __syncthreads();
    int cur = 0;
    for (int k0 = 0; k0 < K; k0 += BK) {
        if (k0 + BK < K) STAGE(cur ^ 1, k0 + BK);
        #pragma unroll
        for (int kk = 0; kk < BK; kk += 32) {
            const int kb = (kk >> 3) + (lane >> 4);
            bf16x8 a[4], b[2];
            #pragma unroll
            for (int i = 0; i < 4; i++) {
                int r = wr * 64 + i * 16 + (lane & 15);
                a[i] = *(const bf16x8*)&As[cur][r * BK + ((kb ^ (r & 7)) << 3)];
            }
            #pragma unroll
            for (int j = 0; j < 2; j++) {
                int cc = wc * 32 + j * 16 + (lane & 15);
                b[j] = *(const bf16x8*)&Bs[cur][cc * BK + ((kb ^ (cc & 7)) << 3)];
            }
            #pragma unroll
            for (int i = 0; i < 4; i++)
                #pragma unroll
                for (int j = 0; j < 2; j++)
                    acc[i][j] = __builtin_amdgcn_mfma_f32_16x16x32_bf16(a[i], b[j], acc[i][j], 0, 0, 0);
        }
        __syncthreads();   // drains vmcnt (next buf staged) + all waves done with cur
        cur ^= 1;
    }
#undef STAGE

    const int lr = lane >> 4, lc = lane & 15;
    #pragma unroll
    for (int i = 0; i < 4; i++) {
        #pragma unroll
        for (int r = 0; r < 4; r++) {
            int row = bm + wr * 64 + i * 16 + lr * 4 + r;
            float rs = 1.0f;
            if (lengths) rs = (t < lengths[row] - 1) ? 1.0f : 0.0f;
            #pragma unroll
            for (int j = 0; j < 2; j++) {
                int col = bn + wc * 32 + j * 16 + lc;
                if (col < N) {
                    float v = (acc[i][j][r] + bias[col]) * rs;
                    if (Cb) Cb[(size_t)row * ldc + col] = f2bf(v);
                    else    Cf[(size_t)row * ldc + col] = v;
                }
            }
        }
    }
}

// ---- one-time prep kernels ------------------------------------------------

// enc fp32 -> bf16, 8 elems/thread
__global__ __launch_bounds__(256) void castenc(const float* __restrict__ in,
                                               short* __restrict__ out)
{
    size_t i8 = ((size_t)blockIdx.x * 256 + threadIdx.x) * 8;
    float4 f0 = *(const float4*)(in + i8);
    float4 f1 = *(const float4*)(in + i8 + 4);
    bf16x8 v;
    v[0] = f2bf(f0.x); v[1] = f2bf(f0.y); v[2] = f2bf(f0.z); v[3] = f2bf(f0.w);
    v[4] = f2bf(f1.x); v[5] = f2bf(f1.y); v[6] = f2bf(f1.z); v[7] = f2bf(f1.w);
    *(bf16x8*)(out + i8) = v;
}

__global__ __launch_bounds__(256) void castk(const float* __restrict__ in,
                                             short* __restrict__ out, int n)
{
    int i4 = (blockIdx.x * 256 + threadIdx.x) * 4;
    if (i4 >= n) return;
    float4 f = *(const float4*)(in + i4);
    out[i4 + 0] = f2bf(f.x); out[i4 + 1] = f2bf(f.y);
    out[i4 + 2] = f2bf(f.z); out[i4 + 3] = f2bf(f.w);
}

// W_df[n][k]: n<512 -> W_dec[n][k], else W_fbeta[n-512][k]   (k<512)
__global__ __launch_bounds__(256) void wdf_kernel(const float* __restrict__ W_dec,
                                                  const float* __restrict__ W_fbeta,
                                                  short* __restrict__ out)
{
    int k = blockIdx.x * 256 + threadIdx.x;
    int n = blockIdx.y;
    float v = (n < A_) ? W_dec[(size_t)n * H_ + k]
                       : W_fbeta[(size_t)(n - A_) * H_ + k];
    out[(size_t)n * H_ + k] = f2bf(v);
}

// W_cat[n][k]: k<2560 -> W_ih[n][k], else W_hh[n][k-2560]
__global__ __launch_bounds__(256) void wcat_kernel(const float* __restrict__ W_ih,
                                                   const float* __restrict__ W_hh,
                                                   short* __restrict__ out)
{
    int k = blockIdx.x * 256 + threadIdx.x;
    int n = blockIdx.y;
    float v = (k < E_ + ENC_) ? W_ih[(size_t)n * (E_ + ENC_) + k]
                              : W_hh[(size_t)n * H_ + (k - (E_ + ENC_))];
    out[(size_t)n * XK_ + k] = f2bf(v);
}

__global__ __launch_bounds__(256) void bdf_kernel(const float* __restrict__ b_dec,
                                                  const float* __restrict__ b_fbeta,
                                                  float* __restrict__ out)
{
    int j = blockIdx.x * 256 + threadIdx.x;
    if (j < NDF_) out[j] = (j < A_) ? b_dec[j] : b_fbeta[j - A_];
}

__global__ __launch_bounds__(256) void bcat_kernel(const float* __restrict__ b_ih,
                                                   const float* __restrict__ b_hh,
                                                   float* __restrict__ out)
{
    int j = blockIdx.x * 256 + threadIdx.x;
    if (j < 4 * H_) out[j] = b_ih[j] + b_hh[j];
}

// meanE_bf[b,e] = bf16( (1/P) sum_p enc_bf[b,p,e] ), 8 cols/thread
__global__ __launch_bounds__(256) void mean_kernel(const short* __restrict__ enc_bf,
                                                   short* __restrict__ meanE_bf)
{
    int g = blockIdx.x * 256 + threadIdx.x;     // B * ENC/8 threads
    int b = g >> 8, cb = g & 255;
    const short* p = enc_bf + (size_t)b * P_ * ENC_ + cb * 8;
    float s[8] = {};
    for (int i = 0; i < P_; i++) {
        bf16x8 v = *(const bf16x8*)(p + (size_t)i * ENC_);
        #pragma unroll
        for (int j = 0; j < 8; j++) s[j] += bf2f(v[j]);
    }
    bf16x8 o;
    #pragma unroll
    for (int j = 0; j < 8; j++) o[j] = f2bf(s[j] * (1.0f / (float)P_));
    *(bf16x8*)(meanE_bf + (size_t)b * ENC_ + cb * 8) = o;
}

// ---- per-step kernels -------------------------------------------------------

__global__ __launch_bounds__(256) void emb_kernel(const int* __restrict__ captions,
                                                  const float* __restrict__ table,
                                                  short* __restrict__ x_in_bf, int t)
{
    int idx = blockIdx.x * 256 + threadIdx.x;
    int b = idx >> 9, col = idx & 511;
    int tok = captions[b * (T_ + 1) + t];
    x_in_bf[(size_t)b * XK_ + col] = f2bf(table[(size_t)tok * E_ + col]);
}

// fused e + softmax: one block per b. e[p] = sum_a relu(att1[b,p,a]+att2[b,a])*w[a]
// (b_full omitted: softmax is shift-invariant)
__global__ __launch_bounds__(256) void esm_kernel(const short* __restrict__ att1_bf,
                                                  const float* __restrict__ attf,
                                                  const float* __restrict__ wfull,
                                                  float* __restrict__ alpha)
{
    __shared__ float es[P_];
    __shared__ float red[256];
    __shared__ float sm, ss;
    const int b = blockIdx.x;
    const int tid = threadIdx.x, wv = tid >> 6, lane = tid & 63;

    float a2v[8], wv8[8];
    const float* a2 = attf + (size_t)b * NDF_;          // att2 part [0:512)
    #pragma unroll
    for (int i = 0; i < 8; i++) {
        a2v[i] = a2[lane * 8 + i];
        wv8[i] = wfull[lane * 8 + i];
    }
    for (int r = 0; r < 49; r++) {
        int row = wv * 49 + r;                          // 4*49 = 196
        bf16x8 a1 = *(const bf16x8*)(att1_bf + ((size_t)b * P_ + row) * A_ + lane * 8);
        float s = 0.0f;
        #pragma unroll
        for (int i = 0; i < 8; i++) {
            float v = bf2f(a1[i]) + a2v[i];
            s += fmaxf(v, 0.0f) * wv8[i];
        }
        #pragma unroll
        for (int off = 32; off > 0; off >>= 1) s += __shfl_down(s, off, 64);
        if (lane == 0) es[row] = s;
    }
    __syncthreads();
    float v = (tid < P_) ? es[tid] : -1e30f;
    red[tid] = v;
    __syncthreads();
    for (int s2 = 128; s2 > 0; s2 >>= 1) {
        if (tid < s2) red[tid] = fmaxf(red[tid], red[tid + s2]);
        __syncthreads();
    }
    if (tid == 0) sm = red[0];
    __syncthreads();
    float ex = (tid < P_) ? expf(v - sm) : 0.0f;
    red[tid] = ex;
    __syncthreads();
    for (int s2 = 128; s2 > 0; s2 >>= 1) {
        if (tid < s2) red[tid] += red[tid + s2];
        __syncthreads();
    }
    if (tid == 0) ss = red[0];
    __syncthreads();
    if (tid < P_) alpha[(size_t)b * P_ + tid] = ex / ss;
}

// x_in_bf[b, E+col] = bf16( sigmoid(fbeta_pre[b,col]) * sum_p alpha[b,p]*enc_bf[b,p,col] )
// 4 cols/thread, grid (ENC/1024, B)
__global__ __launch_bounds__(256) void ctx_kernel(const float* __restrict__ alpha,
                                                  const short* __restrict__ enc_bf,
                                                  const float* __restrict__ attf,
                                                  short* __restrict__ x_in_bf)
{
    __shared__ float al[P_];
    const int b = blockIdx.y;
    const int c0 = blockIdx.x * 1024 + threadIdx.x * 4;
    for (int i = threadIdx.x; i < P_; i += 256) al[i] = alpha[(size_t)b * P_ + i];
    __syncthreads();
    const short* eb = enc_bf + (size_t)b * P_ * ENC_ + c0;
    float s0 = 0, s1 = 0, s2 = 0, s3 = 0;
    for (int p = 0; p < P_; p++) {
        bf16x4 ev = *(const bf16x4*)(eb + (size_t)p * ENC_);
        float a = al[p];
        s0 += a * bf2f(ev[0]); s1 += a * bf2f(ev[1]);
        s2 += a * bf2f(ev[2]); s3 += a * bf2f(ev[3]);
    }
    const float* fb = attf + (size_t)b * NDF_ + A_;     // fbeta part [512:2560)
    short* xo = x_in_bf + (size_t)b * XK_ + E_ + c0;
    xo[0] = f2bf(sigmoidf_(fb[c0 + 0]) * s0);
    xo[1] = f2bf(sigmoidf_(fb[c0 + 1]) * s1);
    xo[2] = f2bf(sigmoidf_(fb[c0 + 2]) * s2);
    xo[3] = f2bf(sigmoidf_(fb[c0 + 3]) * s3);
}

// LSTM pointwise; h (bf16) lives in x_in_bf[:, 2560:3072]
__global__ __launch_bounds__(256) void lstm_kernel(const float* __restrict__ gates,
                                                   float* __restrict__ c,
                                                   short* __restrict__ x_in_bf,
                                                   short* __restrict__ hn_bf,
                                                   const int* __restrict__ lengths, int t)
{
    int idx = blockIdx.x * 256 + threadIdx.x;
    int b = idx >> 9, j = idx & 511;
    const float* g = gates + (size_t)b * 4 * H_;
    float i_ = sigmoidf_(g[j]);
    float f_ = sigmoidf_(g[H_ + j]);
    float g_ = tanhf(g[2 * H_ + j]);
    float o_ = sigmoidf_(g[3 * H_ + j]);
    float cn = f_ * c[idx] + i_ * g_;
    float hv = o_ * tanhf(cn);
    hn_bf[idx] = f2bf(hv);
    if (t < lengths[b] - 1) {
        c[idx] = cn;
        x_in_bf[(size_t)b * XK_ + (E_ + ENC_) + j] = f2bf(hv);
    }
}

extern "C" void kernel_launch(void* const* d_in, const int* in_sizes, int n_in,
                              void* d_out, int out_size, void* d_ws, size_t ws_size,
                              hipStream_t stream)
{
    const float* enc      = (const float*)d_in[0];
    const int*   captions = (const int*)  d_in[1];
    const int*   lengths  = (const int*)  d_in[2];
    const float* W_enc    = (const float*)d_in[3];
    const float* b_enc    = (const float*)d_in[4];
    const float* W_dec    = (const float*)d_in[5];
    const float* b_dec    = (const float*)d_in[6];
    const float* w_full   = (const float*)d_in[7];
    // d_in[8] = b_full: dropped (softmax shift-invariant)
    const float* emb_tab  = (const float*)d_in[9];
    const float* W_ih     = (const float*)d_in[10];
    const float* b_ih     = (const float*)d_in[11];
    const float* W_hh     = (const float*)d_in[12];
    const float* b_hh     = (const float*)d_in[13];
    const float* W_init_h = (const float*)d_in[14];
    const float* b_init_h = (const float*)d_in[15];
    const float* W_init_c = (const float*)d_in[16];
    const float* b_init_c = (const float*)d_in[17];
    const float* W_fbeta  = (const float*)d_in[18];
    const float* b_fbeta  = (const float*)d_in[19];
    const float* W_fc     = (const float*)d_in[20];
    const float* b_fc     = (const float*)d_in[21];
    float* out = (float*)d_out;

    char* ws = (char*)d_ws;
    size_t off = 0;
    auto alloc = [&](size_t bytes) { void* p = ws + off; off += (bytes + 255) & ~(size_t)255; return p; };
    short* enc_bf   = (short*)alloc((size_t)B_ * P_ * ENC_ * 2);   // 102.8 MB
    short* att1_bf  = (short*)alloc((size_t)B_ * P_ * A_ * 2);     // 25.7 MB
    short* Wenc_bf  = (short*)alloc((size_t)A_ * ENC_ * 2);
    short* Wih_bf   = (short*)alloc((size_t)H_ * ENC_ * 2);
    short* Wic_bf   = (short*)alloc((size_t)H_ * ENC_ * 2);
    short* Wdf_bf   = (short*)alloc((size_t)NDF_ * H_ * 2);
    short* Wcat_bf  = (short*)alloc((size_t)4 * H_ * XK_ * 2);     // 12.6 MB
    short* Wfc_bf   = (short*)alloc((size_t)V_ * H_ * 2);          // 10.2 MB
    float* bdf      = (float*)alloc(NDF_ * 4);
    float* bcat     = (float*)alloc(4 * H_ * 4);
    short* meanE_bf = (short*)alloc((size_t)B_ * ENC_ * 2);
    float* cbuf     = (float*)alloc((size_t)B_ * H_ * 4);
    short* hn_bf    = (short*)alloc((size_t)B_ * H_ * 2);
    float* attf     = (float*)alloc((size_t)B_ * NDF_ * 4);
    float* alpha    = (float*)alloc((size_t)B_ * P_ * 4);
    short* x_in_bf  = (short*)alloc((size_t)B_ * XK_ * 2);
    float* gates    = (float*)alloc((size_t)B_ * 4 * H_ * 4);
    (void)ws_size;

    // ---- one-time prep
    castenc<<<(B_ * P_ * ENC_) / (256 * 8), 256, 0, stream>>>(enc, enc_bf);
    castk<<<(A_ * ENC_ / 4 + 255) / 256, 256, 0, stream>>>(W_enc, Wenc_bf, A_ * ENC_);
    castk<<<(H_ * ENC_ / 4 + 255) / 256, 256, 0, stream>>>(W_init_h, Wih_bf, H_ * ENC_);
    castk<<<(H_ * ENC_ / 4 + 255) / 256, 256, 0, stream>>>(W_init_c, Wic_bf, H_ * ENC_);
    castk<<<(V_ * H_ / 4 + 255) / 256, 256, 0, stream>>>(W_fc, Wfc_bf, V_ * H_);
    wdf_kernel<<<dim3(H_ / 256, NDF_), 256, 0, stream>>>(W_dec, W_fbeta, Wdf_bf);
    wcat_kernel<<<dim3(XK_ / 256, 4 * H_), 256, 0, stream>>>(W_ih, W_hh, Wcat_bf);
    bdf_kernel<<<(NDF_ + 255) / 256, 256, 0, stream>>>(b_dec, b_fbeta, bdf);
    bcat_kernel<<<(4 * H_ + 255) / 256, 256, 0, stream>>>(b_ih, b_hh, bcat);
    mean_kernel<<<(B_ * ENC_ / 8) / 256, 256, 0, stream>>>(enc_bf, meanE_bf);

    // att1 = enc @ W_enc^T + b_enc  -> bf16 [25088 x 512], XCD-grouped
    gemm_bf<<<8 * 8 * ((196 + 7) / 8), 256, 0, stream>>>(
        enc_bf, Wenc_bf, nullptr, att1_bf, b_enc,
        A_, ENC_, ENC_, ENC_, A_, 196, 8, nullptr, 0);
    // h0 -> x_in_bf[:, 2560:3072] (bf16), c0 -> cbuf (fp32)
    gemm_bf<<<H_ / BN, 256, 0, stream>>>(
        meanE_bf, Wih_bf, nullptr, x_in_bf + (E_ + ENC_), b_init_h,
        H_, ENC_, ENC_, ENC_, XK_, 1, H_ / BN, nullptr, 0);
    gemm_bf<<<H_ / BN, 256, 0, stream>>>(
        meanE_bf, Wic_bf, cbuf, nullptr, b_init_c,
        H_, ENC_, ENC_, ENC_, H_, 1, H_ / BN, nullptr, 0);

    for (int t = 0; t < T_; t++) {
        emb_kernel<<<(B_ * E_) / 256, 256, 0, stream>>>(captions, emb_tab, x_in_bf, t);
        // attf = h @ [W_dec|W_fbeta]^T + [b_dec|b_fbeta]   [128 x 2560, K=512]
        gemm_bf<<<NDF_ / BN, 256, 0, stream>>>(
            x_in_bf + (E_ + ENC_), Wdf_bf, attf, nullptr, bdf,
            NDF_, H_, XK_, H_, NDF_, 1, NDF_ / BN, nullptr, 0);
        esm_kernel<<<B_, 256, 0, stream>>>(att1_bf, attf, w_full, alpha);
        ctx_kernel<<<dim3(ENC_ / 1024, B_), 256, 0, stream>>>(alpha, enc_bf, attf, x_in_bf);
        // gates = x_in @ [W_ih|W_hh]^T + (b_ih+b_hh)       [128 x 2048, K=3072]
        gemm_bf<<<(4 * H_) / BN, 256, 0, stream>>>(
            x_in_bf, Wcat_bf, gates, nullptr, bcat,
            4 * H_, XK_, XK_, XK_, 4 * H_, 1, (4 * H_) / BN, nullptr, 0);
        lstm_kernel<<<(B_ * H_) / 256, 256, 0, stream>>>(gates, cbuf, x_in_bf, hn_bf, lengths, t);
        // pred_t = (h_new @ W_fc^T + b_fc) * mask -> out[:, t, :]
        gemm_bf<<<(V_ + BN - 1) / BN, 256, 0, stream>>>(
            hn_bf, Wfc_bf, out + (size_t)t * V_, nullptr, b_fc,
            V_, H_, H_, H_, T_ * V_, 1, (V_ + BN - 1) / BN, lengths, t);
    }
}

// Round 4
// 2246.437 us; speedup vs baseline: 7.9077x; 1.2435x over previous
//
#include <hip/hip_runtime.h>
#include <hip/hip_bf16.h>
#include <math.h>

#define B_   128
#define P_   196
#define ENC_ 2048
#define A_   512
#define H_   512
#define E_   512
#define V_   10000
#define T_   20
#define NDF_ 2560   /* fused att2(512) + fbeta(2048) */
#define XK_  3072   /* gates K: E + ENC + H */

typedef __attribute__((ext_vector_type(8))) short bf16x8;
typedef __attribute__((ext_vector_type(4))) short bf16x4;
typedef __attribute__((ext_vector_type(4))) float f32x4;

__device__ __forceinline__ float sigmoidf_(float x) { return 1.0f / (1.0f + expf(-x)); }

__device__ __forceinline__ short f2bf(float f) {
    unsigned u = __float_as_uint(f);
    u += 0x7fffu + ((u >> 16) & 1u);
    return (short)(u >> 16);
}
__device__ __forceinline__ float bf2f(short s) {
    return __uint_as_float(((unsigned)(unsigned short)s) << 16);
}
__device__ __forceinline__ void gload_lds16(const void* g, void* l) {
    __builtin_amdgcn_global_load_lds(
        (const __attribute__((address_space(1))) void*)g,
        (__attribute__((address_space(3))) void*)l, 16, 0, 0);
}

#define BM 128
#define BN 64
#define BK 64

// ---------------------------------------------------------------------------
// Generic GEMM: C[M,N] = A_bf16[M,K] @ B_bf16[N,K]^T + bias[N]
// Double-buffered LDS, XOR-swizzled (pre-swizzled global source).
// mtiles>1: XCD-grouped block decode. pred mode: row r=(t*128+b) -> out[b][t][:]
// with length mask.
// ---------------------------------------------------------------------------
__global__ __launch_bounds__(256) void gemm_bf(
    const short* __restrict__ A, const short* __restrict__ Bw,
    float* __restrict__ Cf, short* __restrict__ Cb,
    const float* __restrict__ bias,
    int N, int K, int lda, int ldb, int ldc,
    int mtiles, int ntiles, int pred,
    const int* __restrict__ lengths)
{
    __shared__ __attribute__((aligned(16))) short As[2][BM * BK];
    __shared__ __attribute__((aligned(16))) short Bs[2][BN * BK];
    int pm, pn;
    if (mtiles == 1) { pm = 0; pn = blockIdx.x; }
    else {
        int xcd = blockIdx.x & 7, s = blockIdx.x >> 3;
        pn = s % ntiles;
        pm = (s / ntiles) * 8 + xcd;
        if (pm >= mtiles) return;
    }
    const int bm = pm * BM, bn = pn * BN;
    const int tid = threadIdx.x, w = tid >> 6, lane = tid & 63;
    const int wr = w >> 1, wc = w & 1;
    const int lr8 = lane >> 3, lk = lane & 7;

    f32x4 zero4 = {0.f, 0.f, 0.f, 0.f};
    f32x4 acc[4][2];
    #pragma unroll
    for (int i = 0; i < 4; i++)
        #pragma unroll
        for (int j = 0; j < 2; j++) acc[i][j] = zero4;

#define STAGE(buf, k0) {                                                        \
    _Pragma("unroll")                                                           \
    for (int i = 0; i < 4; i++) {                                               \
        int row0 = w * 32 + i * 8; int row = row0 + lr8;                        \
        const short* ga = A + (size_t)(bm + row) * lda + (k0)                   \
                          + ((lk ^ (row & 7)) << 3);                            \
        gload_lds16(ga, &As[buf][row0 * BK]);                                   \
    }                                                                           \
    _Pragma("unroll")                                                           \
    for (int i = 0; i < 2; i++) {                                               \
        int row0 = w * 16 + i * 8; int row = row0 + lr8;                        \
        int gn = bn + row; if (gn > N - 1) gn = N - 1;                          \
        const short* gb = Bw + (size_t)gn * ldb + (k0)                          \
                          + ((lk ^ (row & 7)) << 3);                            \
        gload_lds16(gb, &Bs[buf][row0 * BK]);                                   \
    } }

    STAGE(0, 0);
    __syncthreads();
    int cur = 0;
    for (int k0 = 0; k0 < K; k0 += BK) {
        if (k0 + BK < K) STAGE(cur ^ 1, k0 + BK);
        #pragma unroll
        for (int kk = 0; kk < BK; kk += 32) {
            const int kb = (kk >> 3) + (lane >> 4);
            bf16x8 a[4], b[2];
            #pragma unroll
            for (int i = 0; i < 4; i++) {
                int r = wr * 64 + i * 16 + (lane & 15);
                a[i] = *(const bf16x8*)&As[cur][r * BK + ((kb ^ (r & 7)) << 3)];
            }
            #pragma unroll
            for (int j = 0; j < 2; j++) {
                int cc = wc * 32 + j * 16 + (lane & 15);
                b[j] = *(const bf16x8*)&Bs[cur][cc * BK + ((kb ^ (cc & 7)) << 3)];
            }
            #pragma unroll
            for (int i = 0; i < 4; i++)
                #pragma unroll
                for (int j = 0; j < 2; j++)
                    acc[i][j] = __builtin_amdgcn_mfma_f32_16x16x32_bf16(a[i], b[j], acc[i][j], 0, 0, 0);
        }
        __syncthreads();
        cur ^= 1;
    }
#undef STAGE

    const int lr = lane >> 4, lc = lane & 15;
    #pragma unroll
    for (int i = 0; i < 4; i++) {
        #pragma unroll
        for (int r = 0; r < 4; r++) {
            int row = bm + wr * 64 + i * 16 + lr * 4 + r;
            #pragma unroll
            for (int j = 0; j < 2; j++) {
                int col = bn + wc * 32 + j * 16 + lc;
                if (col >= N) continue;
                float v = acc[i][j][r] + bias[col];
                if (pred) {
                    int tt = row >> 7, bb = row & 127;
                    float rs = (tt < lengths[bb] - 1) ? 1.0f : 0.0f;
                    Cf[(size_t)bb * T_ * V_ + (size_t)tt * V_ + col] = v * rs;
                } else if (Cb) {
                    Cb[(size_t)row * ldc + col] = f2bf(v);
                } else {
                    Cf[(size_t)row * ldc + col] = v;
                }
            }
        }
    }
}

// ---------------------------------------------------------------------------
// gates GEMM [128 x 2048, K=3072] with gate-interleaved W (col n' = 4*j+g)
// + fused LSTM epilogue. A streams from {emb_all[t] | ctxbuf | hbuf} by K-range.
// ---------------------------------------------------------------------------
__global__ __launch_bounds__(256) void gates_lstm(
    const short* __restrict__ embA,    // [128][512]  (emb_all + t*B*E)
    const short* __restrict__ ctxbuf,  // [128][2048]
    short* __restrict__ hbuf,          // [128][512]  in/out
    const short* __restrict__ Wcat,    // [2048][3072] interleaved rows
    const float* __restrict__ bcat,    // [2048] interleaved
    float* __restrict__ cbuf,          // [128][512]  in/out
    short* __restrict__ hn_t,          // [128][512]  hn_all + t*B*H
    const int* __restrict__ lengths, int t)
{
    __shared__ __attribute__((aligned(16))) char smem[49152];
    short* As0 = (short*)smem;               // [2][BM*BK] = 32 KB
    short* Bs0 = (short*)(smem + 32768);     // [2][BN*BK] = 16 KB
    const int bn = blockIdx.x * BN;
    const int tid = threadIdx.x, w = tid >> 6, lane = tid & 63;
    const int wr = w >> 1, wc = w & 1;
    const int lr8 = lane >> 3, lk = lane & 7;

    f32x4 zero4 = {0.f, 0.f, 0.f, 0.f};
    f32x4 acc[4][2];
    #pragma unroll
    for (int i = 0; i < 4; i++)
        #pragma unroll
        for (int j = 0; j < 2; j++) acc[i][j] = zero4;

#define STAGE_G(buf, k0) {                                                      \
    const short* Ap; int Al, kk0;                                               \
    if ((k0) < 512)       { Ap = embA;   Al = 512;  kk0 = (k0); }               \
    else if ((k0) < 2560) { Ap = ctxbuf; Al = 2048; kk0 = (k0) - 512; }         \
    else                  { Ap = hbuf;   Al = 512;  kk0 = (k0) - 2560; }        \
    _Pragma("unroll")                                                           \
    for (int i = 0; i < 4; i++) {                                               \
        int row0 = w * 32 + i * 8; int row = row0 + lr8;                        \
        gload_lds16(Ap + (size_t)row * Al + kk0 + ((lk ^ (row & 7)) << 3),      \
                    &As0[(buf) * (BM * BK) + row0 * BK]);                       \
    }                                                                           \
    _Pragma("unroll")                                                           \
    for (int i = 0; i < 2; i++) {                                               \
        int row0 = w * 16 + i * 8; int row = row0 + lr8;                        \
        gload_lds16(Wcat + (size_t)(bn + row) * XK_ + (k0)                      \
                    + ((lk ^ (row & 7)) << 3),                                  \
                    &Bs0[(buf) * (BN * BK) + row0 * BK]);                       \
    } }

    STAGE_G(0, 0);
    __syncthreads();
    int cur = 0;
    for (int k0 = 0; k0 < XK_; k0 += BK) {
        if (k0 + BK < XK_) STAGE_G(cur ^ 1, k0 + BK);
        #pragma unroll
        for (int kk = 0; kk < BK; kk += 32) {
            const int kb = (kk >> 3) + (lane >> 4);
            bf16x8 a[4], b[2];
            #pragma unroll
            for (int i = 0; i < 4; i++) {
                int r = wr * 64 + i * 16 + (lane & 15);
                a[i] = *(const bf16x8*)&As0[cur * (BM * BK) + r * BK + ((kb ^ (r & 7)) << 3)];
            }
            #pragma unroll
            for (int j = 0; j < 2; j++) {
                int cc = wc * 32 + j * 16 + (lane & 15);
                b[j] = *(const bf16x8*)&Bs0[cur * (BN * BK) + cc * BK + ((kb ^ (cc & 7)) << 3)];
            }
            #pragma unroll
            for (int i = 0; i < 4; i++)
                #pragma unroll
                for (int j = 0; j < 2; j++)
                    acc[i][j] = __builtin_amdgcn_mfma_f32_16x16x32_bf16(a[i], b[j], acc[i][j], 0, 0, 0);
        }
        __syncthreads();
        cur ^= 1;
    }
#undef STAGE_G

    // epilogue: gates tile -> LDS (fp32, stride 68), then LSTM pointwise
    float* gl = (float*)smem;                 // 128*68*4 = 34816 B (overlaps As+Bs, both dead)
    const int lr = lane >> 4, lc = lane & 15;
    #pragma unroll
    for (int i = 0; i < 4; i++) {
        #pragma unroll
        for (int r = 0; r < 4; r++) {
            int row = wr * 64 + i * 16 + lr * 4 + r;
            #pragma unroll
            for (int j = 0; j < 2; j++) {
                int col = wc * 32 + j * 16 + lc;
                gl[row * 68 + col] = acc[i][j][r] + bcat[bn + col];
            }
        }
    }
    __syncthreads();
    #pragma unroll
    for (int q = 0; q < 8; q++) {
        int id  = tid * 8 + q;        // 0..2047
        int row = id >> 4;            // batch b
        int j   = id & 15;            // local hidden unit
        int jg  = (bn >> 2) + j;      // global hidden index
        float i_ = sigmoidf_(gl[row * 68 + 4 * j + 0]);
        float f_ = sigmoidf_(gl[row * 68 + 4 * j + 1]);
        float g_ = tanhf    (gl[row * 68 + 4 * j + 2]);
        float o_ = sigmoidf_(gl[row * 68 + 4 * j + 3]);
        float cn = f_ * cbuf[row * H_ + jg] + i_ * g_;
        float hv = o_ * tanhf(cn);
        hn_t[row * H_ + jg] = f2bf(hv);
        if (t < lengths[row] - 1) {
            cbuf[row * H_ + jg] = cn;
            hbuf[row * H_ + jg] = f2bf(hv);
        }
    }
}

// ---------------------------------------------------------------------------
// fused e + softmax + context: grid (2, B). alpha stays in LDS.
// ---------------------------------------------------------------------------
__global__ __launch_bounds__(256) void esmctx_kernel(
    const short* __restrict__ att1_bf, const float* __restrict__ attf,
    const float* __restrict__ wfull, const short* __restrict__ enc_bf,
    short* __restrict__ ctxbuf)
{
    __shared__ float es[P_];
    __shared__ float red[256];
    __shared__ float al[P_];
    __shared__ float sm, ss;
    const int b = blockIdx.y, half = blockIdx.x;
    const int tid = threadIdx.x, wv = tid >> 6, lane = tid & 63;

    float a2v[8], wv8[8];
    const float* a2 = attf + (size_t)b * NDF_;
    #pragma unroll
    for (int i = 0; i < 8; i++) {
        a2v[i] = a2[lane * 8 + i];
        wv8[i] = wfull[lane * 8 + i];
    }
    for (int r = 0; r < 49; r++) {
        int row = wv * 49 + r;
        bf16x8 a1 = *(const bf16x8*)(att1_bf + ((size_t)b * P_ + row) * A_ + lane * 8);
        float s = 0.0f;
        #pragma unroll
        for (int i = 0; i < 8; i++) {
            float v = bf2f(a1[i]) + a2v[i];
            s += fmaxf(v, 0.0f) * wv8[i];
        }
        #pragma unroll
        for (int off = 32; off > 0; off >>= 1) s += __shfl_down(s, off, 64);
        if (lane == 0) es[row] = s;
    }
    __syncthreads();
    float v = (tid < P_) ? es[tid] : -1e30f;
    red[tid] = v;
    __syncthreads();
    for (int s2 = 128; s2 > 0; s2 >>= 1) {
        if (tid < s2) red[tid] = fmaxf(red[tid], red[tid + s2]);
        __syncthreads();
    }
    if (tid == 0) sm = red[0];
    __syncthreads();
    float ex = (tid < P_) ? expf(v - sm) : 0.0f;
    red[tid] = ex;
    __syncthreads();
    for (int s2 = 128; s2 > 0; s2 >>= 1) {
        if (tid < s2) red[tid] += red[tid + s2];
        __syncthreads();
    }
    if (tid == 0) ss = red[0];
    __syncthreads();
    if (tid < P_) al[tid] = ex / ss;
    __syncthreads();

    const int c0 = half * 1024 + tid * 4;
    const short* eb = enc_bf + (size_t)b * P_ * ENC_ + c0;
    float s0 = 0, s1 = 0, s2 = 0, s3 = 0;
    for (int p = 0; p < P_; p++) {
        bf16x4 ev = *(const bf16x4*)(eb + (size_t)p * ENC_);
        float a = al[p];
        s0 += a * bf2f(ev[0]); s1 += a * bf2f(ev[1]);
        s2 += a * bf2f(ev[2]); s3 += a * bf2f(ev[3]);
    }
    const float* fb = attf + (size_t)b * NDF_ + A_;
    short* xo = ctxbuf + (size_t)b * ENC_ + c0;
    xo[0] = f2bf(sigmoidf_(fb[c0 + 0]) * s0);
    xo[1] = f2bf(sigmoidf_(fb[c0 + 1]) * s1);
    xo[2] = f2bf(sigmoidf_(fb[c0 + 2]) * s2);
    xo[3] = f2bf(sigmoidf_(fb[c0 + 3]) * s3);
}

// ---- one-time prep kernels ------------------------------------------------

__global__ __launch_bounds__(256) void castenc(const float* __restrict__ in,
                                               short* __restrict__ out)
{
    size_t i8 = ((size_t)blockIdx.x * 256 + threadIdx.x) * 8;
    float4 f0 = *(const float4*)(in + i8);
    float4 f1 = *(const float4*)(in + i8 + 4);
    bf16x8 v;
    v[0] = f2bf(f0.x); v[1] = f2bf(f0.y); v[2] = f2bf(f0.z); v[3] = f2bf(f0.w);
    v[4] = f2bf(f1.x); v[5] = f2bf(f1.y); v[6] = f2bf(f1.z); v[7] = f2bf(f1.w);
    *(bf16x8*)(out + i8) = v;
}

__global__ __launch_bounds__(256) void castk(const float* __restrict__ in,
                                             short* __restrict__ out, int n)
{
    int i4 = (blockIdx.x * 256 + threadIdx.x) * 4;
    if (i4 >= n) return;
    float4 f = *(const float4*)(in + i4);
    out[i4 + 0] = f2bf(f.x); out[i4 + 1] = f2bf(f.y);
    out[i4 + 2] = f2bf(f.z); out[i4 + 3] = f2bf(f.w);
}

__global__ __launch_bounds__(256) void wdf_kernel(const float* __restrict__ W_dec,
                                                  const float* __restrict__ W_fbeta,
                                                  short* __restrict__ out)
{
    int k = blockIdx.x * 256 + threadIdx.x;
    int n = blockIdx.y;
    float v = (n < A_) ? W_dec[(size_t)n * H_ + k]
                       : W_fbeta[(size_t)(n - A_) * H_ + k];
    out[(size_t)n * H_ + k] = f2bf(v);
}

// gate-interleaved W_cat: out row n' = 4*j+g  <- source row g*512+j
__global__ __launch_bounds__(256) void wcat_kernel(const float* __restrict__ W_ih,
                                                   const float* __restrict__ W_hh,
                                                   short* __restrict__ out)
{
    int k = blockIdx.x * 256 + threadIdx.x;
    int n = blockIdx.y;                       // n' 0..2047
    int srow = (n & 3) * H_ + (n >> 2);
    float v = (k < E_ + ENC_) ? W_ih[(size_t)srow * (E_ + ENC_) + k]
                              : W_hh[(size_t)srow * H_ + (k - (E_ + ENC_))];
    out[(size_t)n * XK_ + k] = f2bf(v);
}

__global__ __launch_bounds__(256) void bdf_kernel(const float* __restrict__ b_dec,
                                                  const float* __restrict__ b_fbeta,
                                                  float* __restrict__ out)
{
    int j = blockIdx.x * 256 + threadIdx.x;
    if (j < NDF_) out[j] = (j < A_) ? b_dec[j] : b_fbeta[j - A_];
}

__global__ __launch_bounds__(256) void bcat_kernel(const float* __restrict__ b_ih,
                                                   const float* __restrict__ b_hh,
                                                   float* __restrict__ out)
{
    int j = blockIdx.x * 256 + threadIdx.x;   // interleaved index
    if (j < 4 * H_) {
        int srow = (j & 3) * H_ + (j >> 2);
        out[j] = b_ih[srow] + b_hh[srow];
    }
}

__global__ __launch_bounds__(256) void mean_kernel(const short* __restrict__ enc_bf,
                                                   short* __restrict__ meanE_bf)
{
    int g = blockIdx.x * 256 + threadIdx.x;
    int b = g >> 8, cb = g & 255;
    const short* p = enc_bf + (size_t)b * P_ * ENC_ + cb * 8;
    float s[8] = {};
    for (int i = 0; i < P_; i++) {
        bf16x8 v = *(const bf16x8*)(p + (size_t)i * ENC_);
        #pragma unroll
        for (int j = 0; j < 8; j++) s[j] += bf2f(v[j]);
    }
    bf16x8 o;
    #pragma unroll
    for (int j = 0; j < 8; j++) o[j] = f2bf(s[j] * (1.0f / (float)P_));
    *(bf16x8*)(meanE_bf + (size_t)b * ENC_ + cb * 8) = o;
}

// all-steps embedding gather: emb_all[t][b][col]
__global__ __launch_bounds__(256) void emball_kernel(const int* __restrict__ captions,
                                                     const float* __restrict__ table,
                                                     short* __restrict__ emb_all)
{
    int idx = blockIdx.x * 256 + threadIdx.x;   // T*B*E
    int col = idx & 511;
    int bt  = idx >> 9;
    int b   = bt & 127;
    int t   = bt >> 7;
    int tok = captions[b * (T_ + 1) + t];
    emb_all[(size_t)t * B_ * E_ + (size_t)b * E_ + col] = f2bf(table[(size_t)tok * E_ + col]);
}

extern "C" void kernel_launch(void* const* d_in, const int* in_sizes, int n_in,
                              void* d_out, int out_size, void* d_ws, size_t ws_size,
                              hipStream_t stream)
{
    const float* enc      = (const float*)d_in[0];
    const int*   captions = (const int*)  d_in[1];
    const int*   lengths  = (const int*)  d_in[2];
    const float* W_enc    = (const float*)d_in[3];
    const float* b_enc    = (const float*)d_in[4];
    const float* W_dec    = (const float*)d_in[5];
    const float* b_dec    = (const float*)d_in[6];
    const float* w_full   = (const float*)d_in[7];
    // d_in[8] = b_full: dropped (softmax shift-invariant)
    const float* emb_tab  = (const float*)d_in[9];
    const float* W_ih     = (const float*)d_in[10];
    const float* b_ih     = (const float*)d_in[11];
    const float* W_hh     = (const float*)d_in[12];
    const float* b_hh     = (const float*)d_in[13];
    const float* W_init_h = (const float*)d_in[14];
    const float* b_init_h = (const float*)d_in[15];
    const float* W_init_c = (const float*)d_in[16];
    const float* b_init_c = (const float*)d_in[17];
    const float* W_fbeta  = (const float*)d_in[18];
    const float* b_fbeta  = (const float*)d_in[19];
    const float* W_fc     = (const float*)d_in[20];
    const float* b_fc     = (const float*)d_in[21];
    float* out = (float*)d_out;

    char* ws = (char*)d_ws;
    size_t off = 0;
    auto alloc = [&](size_t bytes) { void* p = ws + off; off += (bytes + 255) & ~(size_t)255; return p; };
    short* enc_bf   = (short*)alloc((size_t)B_ * P_ * ENC_ * 2);
    short* att1_bf  = (short*)alloc((size_t)B_ * P_ * A_ * 2);
    short* Wenc_bf  = (short*)alloc((size_t)A_ * ENC_ * 2);
    short* Wih_bf   = (short*)alloc((size_t)H_ * ENC_ * 2);
    short* Wic_bf   = (short*)alloc((size_t)H_ * ENC_ * 2);
    short* Wdf_bf   = (short*)alloc((size_t)NDF_ * H_ * 2);
    short* Wcat_bf  = (short*)alloc((size_t)4 * H_ * XK_ * 2);
    short* Wfc_bf   = (short*)alloc((size_t)V_ * H_ * 2);
    float* bdf      = (float*)alloc(NDF_ * 4);
    float* bcat     = (float*)alloc(4 * H_ * 4);
    short* meanE_bf = (short*)alloc((size_t)B_ * ENC_ * 2);
    float* cbuf     = (float*)alloc((size_t)B_ * H_ * 4);
    short* hbuf     = (short*)alloc((size_t)B_ * H_ * 2);
    short* emb_all  = (short*)alloc((size_t)T_ * B_ * E_ * 2);
    short* hn_all   = (short*)alloc((size_t)T_ * B_ * H_ * 2);
    float* attf     = (float*)alloc((size_t)B_ * NDF_ * 4);
    short* ctxbuf   = (short*)alloc((size_t)B_ * ENC_ * 2);
    (void)ws_size;

    // ---- one-time prep
    castenc<<<(B_ * P_ * ENC_) / (256 * 8), 256, 0, stream>>>(enc, enc_bf);
    castk<<<(A_ * ENC_ / 4 + 255) / 256, 256, 0, stream>>>(W_enc, Wenc_bf, A_ * ENC_);
    castk<<<(H_ * ENC_ / 4 + 255) / 256, 256, 0, stream>>>(W_init_h, Wih_bf, H_ * ENC_);
    castk<<<(H_ * ENC_ / 4 + 255) / 256, 256, 0, stream>>>(W_init_c, Wic_bf, H_ * ENC_);
    castk<<<(V_ * H_ / 4 + 255) / 256, 256, 0, stream>>>(W_fc, Wfc_bf, V_ * H_);
    wdf_kernel<<<dim3(H_ / 256, NDF_), 256, 0, stream>>>(W_dec, W_fbeta, Wdf_bf);
    wcat_kernel<<<dim3(XK_ / 256, 4 * H_), 256, 0, stream>>>(W_ih, W_hh, Wcat_bf);
    bdf_kernel<<<(NDF_ + 255) / 256, 256, 0, stream>>>(b_dec, b_fbeta, bdf);
    bcat_kernel<<<(4 * H_ + 255) / 256, 256, 0, stream>>>(b_ih, b_hh, bcat);
    mean_kernel<<<(B_ * ENC_ / 8) / 256, 256, 0, stream>>>(enc_bf, meanE_bf);
    emball_kernel<<<(T_ * B_ * E_) / 256, 256, 0, stream>>>(captions, emb_tab, emb_all);

    // att1 = enc @ W_enc^T + b_enc -> bf16, XCD-grouped
    gemm_bf<<<8 * 8 * ((196 + 7) / 8), 256, 0, stream>>>(
        enc_bf, Wenc_bf, nullptr, att1_bf, b_enc,
        A_, ENC_, ENC_, ENC_, A_, 196, 8, 0, nullptr);
    // h0 -> hbuf (bf16), c0 -> cbuf (fp32)
    gemm_bf<<<H_ / BN, 256, 0, stream>>>(
        meanE_bf, Wih_bf, nullptr, hbuf, b_init_h,
        H_, ENC_, ENC_, ENC_, H_, 1, H_ / BN, 0, nullptr);
    gemm_bf<<<H_ / BN, 256, 0, stream>>>(
        meanE_bf, Wic_bf, cbuf, nullptr, b_init_c,
        H_, ENC_, ENC_, ENC_, H_, 1, H_ / BN, 0, nullptr);

    for (int t = 0; t < T_; t++) {
        // attf = h @ [W_dec|W_fbeta]^T + [b_dec|b_fbeta]
        gemm_bf<<<NDF_ / BN, 256, 0, stream>>>(
            hbuf, Wdf_bf, attf, nullptr, bdf,
            NDF_, H_, H_, H_, NDF_, 1, NDF_ / BN, 0, nullptr);
        esmctx_kernel<<<dim3(2, B_), 256, 0, stream>>>(att1_bf, attf, w_full, enc_bf, ctxbuf);
        gates_lstm<<<(4 * H_) / BN, 256, 0, stream>>>(
            emb_all + (size_t)t * B_ * E_, ctxbuf, hbuf, Wcat_bf, bcat,
            cbuf, hn_all + (size_t)t * B_ * H_, lengths, t);
    }
    // pred: [T*B, V] in one GEMM, remapped to out[b][t][:] with mask
    gemm_bf<<<8 * 157 * (((T_ * B_) / BM + 7) / 8), 256, 0, stream>>>(
        hn_all, Wfc_bf, out, nullptr, b_fc,
        V_, H_, H_, H_, 0, (T_ * B_) / BM, 157, 1, lengths);
}